// Round 2
// baseline (68332.648 us; speedup 1.0000x reference)
//
#include <hip/hip_runtime.h>

typedef unsigned int u32;

constexpr int Bc = 32;     // batch
constexpr int Tc = 128;    // encoder seq len
constexpr int Ec = 512;    // embed dim
constexpr int Hc = 1024;   // hidden
constexpr int Vc = 32000;  // vocab
constexpr int Lc = 64;     // max_len (decoder steps)
constexpr int NBLK = 512;  // persistent grid

__device__ __forceinline__ void ldf8(const float* p, float* x) {
    float4 a = *(const float4*)p;
    float4 b = *(const float4*)(p + 4);
    x[0] = a.x; x[1] = a.y; x[2] = a.z; x[3] = a.w;
    x[4] = b.x; x[5] = b.y; x[6] = b.z; x[7] = b.w;
}
__device__ __forceinline__ float sigm(float x) { return 1.0f / (1.0f + expf(-x)); }

// ---------------------------------------------------------------------------
// Software grid barrier (plain launch, graph-capture-safe).
// Generation-counter barrier; cnt self-resets each use (by the last arriver,
// BEFORE gen is bumped), gen is monotonic across launches -> replay-safe.
// __threadfence() = agent-scope fence: publishes this block's writes and
// invalidates stale L1/L2 lines (cross-XCD visibility, G16).
// ---------------------------------------------------------------------------
__device__ __align__(128) u32 g_cnt = 0;
__device__ __align__(128) u32 g_gen = 0;

__device__ __forceinline__ void gsync() {
    __syncthreads();
    if (threadIdx.x == 0) {
        __threadfence();   // release: make this block's writes device-visible
        const u32 g = __hip_atomic_load(&g_gen, __ATOMIC_RELAXED,
                                        __HIP_MEMORY_SCOPE_AGENT);
        const u32 old = __hip_atomic_fetch_add(&g_cnt, 1u, __ATOMIC_ACQ_REL,
                                               __HIP_MEMORY_SCOPE_AGENT);
        if (old == NBLK - 1) {
            // all blocks arrived: reset cnt for next use, then open the gate
            __hip_atomic_store(&g_cnt, 0u, __ATOMIC_RELAXED,
                               __HIP_MEMORY_SCOPE_AGENT);
            __hip_atomic_fetch_add(&g_gen, 1u, __ATOMIC_RELEASE,
                                   __HIP_MEMORY_SCOPE_AGENT);
        } else {
            while (__hip_atomic_load(&g_gen, __ATOMIC_RELAXED,
                                     __HIP_MEMORY_SCOPE_AGENT) == g) {
                __builtin_amdgcn_s_sleep(2);
            }
        }
        __threadfence();   // acquire: invalidate stale cached lines
    }
    __syncthreads();
}

// ---------------------------------------------------------------------------
// Fused LSTM cell phase: g = x@Wih^T + h@Whh^T + b ; gates ; h_out, c.
// XMODE 0: x = fp32 buffer [B][KX]
// XMODE 1: x = emb[src[b*T + tcol]]
// XMODE 2: x = emb[tok[b]]
// Mapping: 512 blocks x 2 hk, 256 thr = 4 k-quarters x (32 b x 2 hk).
// ---------------------------------------------------------------------------
template<int KX, int XMODE>
__device__ __forceinline__ void cell_phase(
    const float* __restrict__ Wih, const float* __restrict__ Whh,
    const float* __restrict__ bias,
    const float* __restrict__ xbuf, const float* __restrict__ emb,
    const int* __restrict__ src, int tcol, const int* __restrict__ tok,
    const float* __restrict__ h_in, float* __restrict__ h_out,
    float* __restrict__ c, float (&red)[4][64][4])
{
    const int tid = threadIdx.x;
    const int q   = tid >> 6;          // k-quarter 0..3
    const int oid = tid & 63;
    const int b   = oid & 31;
    const int hj  = oid >> 5;          // 0..1
    const int hk  = blockIdx.x * 2 + hj;

    const float* w0 = Wih + (size_t)(0 * Hc + hk) * KX;
    const float* w1 = Wih + (size_t)(1 * Hc + hk) * KX;
    const float* w2 = Wih + (size_t)(2 * Hc + hk) * KX;
    const float* w3 = Wih + (size_t)(3 * Hc + hk) * KX;
    const float* u0 = Whh + (size_t)(0 * Hc + hk) * Hc;
    const float* u1 = Whh + (size_t)(1 * Hc + hk) * Hc;
    const float* u2 = Whh + (size_t)(2 * Hc + hk) * Hc;
    const float* u3 = Whh + (size_t)(3 * Hc + hk) * Hc;

    float a0 = 0.f, a1 = 0.f, a2 = 0.f, a3 = 0.f;
    float xv[8], w[8];

    // ---- x contribution ----
    const float* xrow = nullptr;
    if constexpr (XMODE == 0) {
        xrow = xbuf + b * KX;
    } else if constexpr (XMODE == 1) {
        xrow = emb + (size_t)src[b * Tc + tcol] * Ec;
    } else {
        xrow = emb + (size_t)tok[b] * Ec;
    }
    {
        const int kq = KX / 4;
        for (int k = q * kq; k < q * kq + kq; k += 8) {
            ldf8(xrow + k, xv);
            ldf8(w0 + k, w);
            #pragma unroll
            for (int i = 0; i < 8; i++) a0 += w[i] * xv[i];
            ldf8(w1 + k, w);
            #pragma unroll
            for (int i = 0; i < 8; i++) a1 += w[i] * xv[i];
            ldf8(w2 + k, w);
            #pragma unroll
            for (int i = 0; i < 8; i++) a2 += w[i] * xv[i];
            ldf8(w3 + k, w);
            #pragma unroll
            for (int i = 0; i < 8; i++) a3 += w[i] * xv[i];
        }
    }
    // ---- h contribution ----
    {
        const float* hrow = h_in + b * Hc;
        const int kq = Hc / 4;   // 256
        for (int k = q * kq; k < q * kq + kq; k += 8) {
            ldf8(hrow + k, xv);
            ldf8(u0 + k, w);
            #pragma unroll
            for (int i = 0; i < 8; i++) a0 += w[i] * xv[i];
            ldf8(u1 + k, w);
            #pragma unroll
            for (int i = 0; i < 8; i++) a1 += w[i] * xv[i];
            ldf8(u2 + k, w);
            #pragma unroll
            for (int i = 0; i < 8; i++) a2 += w[i] * xv[i];
            ldf8(u3 + k, w);
            #pragma unroll
            for (int i = 0; i < 8; i++) a3 += w[i] * xv[i];
        }
    }

    red[q][oid][0] = a0; red[q][oid][1] = a1;
    red[q][oid][2] = a2; red[q][oid][3] = a3;
    __syncthreads();
    if (q == 0) {
        #pragma unroll
        for (int qq = 1; qq < 4; qq++) {
            a0 += red[qq][oid][0]; a1 += red[qq][oid][1];
            a2 += red[qq][oid][2]; a3 += red[qq][oid][3];
        }
        a0 += bias[0 * Hc + hk];
        a1 += bias[1 * Hc + hk];
        a2 += bias[2 * Hc + hk];
        a3 += bias[3 * Hc + hk];
        const float ig = sigm(a0), fg = sigm(a1);
        const float gv = tanhf(a2), og = sigm(a3);
        const int idx = b * Hc + hk;
        const float cn = fg * c[idx] + ig * gv;
        c[idx] = cn;
        h_out[idx] = og * tanhf(cn);
    }
}

// ---------------------------------------------------------------------------
// logits phase: logits = h1 @ out_W^T + out_b ; fp32 out; per-block argmax
// partials. Blocks 0..499 participate (500 x 64 vocab cols).
// ---------------------------------------------------------------------------
__device__ __forceinline__ void logits_phase(
    const float* __restrict__ h1, const float* __restrict__ outW,
    const float* __restrict__ outb, float* __restrict__ out, int s,
    float* __restrict__ pmax, int* __restrict__ pidx,
    float (&hl)[32][68], float (&sval)[256], int (&sidx)[256])
{
    const int tid = threadIdx.x;
    const int bq  = tid >> 3;        // batch row 0..31
    const int vl  = tid & 7;         // vocab lane 0..7
    const int v0  = blockIdx.x * 64;

    float acc[8];
    #pragma unroll
    for (int j = 0; j < 8; j++) acc[j] = 0.f;

    const float* wbase = outW + (size_t)(v0 + vl * 8) * Hc;

    for (int kc = 0; kc < 16; kc++) {
        #pragma unroll
        for (int i = 0; i < 2; i++) {
            const int idx4 = tid + i * 256;
            const int bb = idx4 >> 4, kq = idx4 & 15;
            *(float4*)&hl[bb][kq * 4] =
                *(const float4*)(h1 + bb * Hc + kc * 64 + kq * 4);
        }
        __syncthreads();
        #pragma unroll
        for (int i8 = 0; i8 < 8; i8++) {
            float h8[8];
            *(float4*)&h8[0] = *(const float4*)&hl[bq][i8 * 8];
            *(float4*)&h8[4] = *(const float4*)&hl[bq][i8 * 8 + 4];
            const float* wk = wbase + kc * 64 + i8 * 8;
            #pragma unroll
            for (int j = 0; j < 8; j++) {
                float w[8]; ldf8(wk + (size_t)j * Hc, w);
                float t = acc[j];
                #pragma unroll
                for (int i = 0; i < 8; i++) t += w[i] * h8[i];
                acc[j] = t;
            }
        }
        __syncthreads();
    }

    float best = -3.4e38f; int bidx = 0;
    alignas(16) float ob[8];
    #pragma unroll
    for (int j = 0; j < 8; j++) {
        const int v = v0 + vl * 8 + j;
        const float val = acc[j] + outb[v];
        ob[j] = val;
        if (val > best) { best = val; bidx = v; }   // ascending v: '>' = first occurrence
    }
    float* dst = out + (size_t)(bq * Lc + s) * Vc + v0 + vl * 8;
    *(float4*)dst       = *(const float4*)&ob[0];
    *(float4*)(dst + 4) = *(const float4*)&ob[4];

    sval[tid] = best; sidx[tid] = bidx;
    __syncthreads();
    if (vl == 0) {
        #pragma unroll
        for (int u = 1; u < 8; u++) {
            const float v2 = sval[tid + u]; const int i2 = sidx[tid + u];
            if (v2 > best || (v2 == best && i2 < bidx)) { best = v2; bidx = i2; }
        }
        pmax[blockIdx.x * 32 + bq] = best;
        pidx[blockIdx.x * 32 + bq] = bidx;
    }
}

// ---------------------------------------------------------------------------
// final argmax phase: blocks 0..31, one batch row each, reduce 500 partials.
// ---------------------------------------------------------------------------
__device__ __forceinline__ void argmax_phase(
    const float* __restrict__ pmax, const int* __restrict__ pidx,
    int* __restrict__ tok, float (&sv)[256], int (&si)[256])
{
    const int b = blockIdx.x, tid = threadIdx.x;
    float best = -3.4e38f; int bidx = 0x7fffffff;
    for (int j = tid; j < 500; j += 256) {
        const float v = pmax[j * 32 + b]; const int i = pidx[j * 32 + b];
        if (v > best || (v == best && i < bidx)) { best = v; bidx = i; }
    }
    sv[tid] = best; si[tid] = bidx;
    __syncthreads();
    for (int st = 128; st > 0; st >>= 1) {
        if (tid < st) {
            const float v = sv[tid + st]; const int i = si[tid + st];
            if (v > sv[tid] || (v == sv[tid] && i < si[tid])) { sv[tid] = v; si[tid] = i; }
        }
        __syncthreads();
    }
    if (tid == 0) tok[b] = si[0];
}

// ---------------------------------------------------------------------------
// ONE persistent kernel (plain launch + software grid barrier):
// init + 128 encoder steps + 64 decode steps.
// 512 blocks x 256 threads = 2 blocks/CU (co-resident by __launch_bounds__).
// ---------------------------------------------------------------------------
__global__ __launch_bounds__(256, 2)
void seq2seq_k(const int* __restrict__ src, const float* __restrict__ emb,
               const float* __restrict__ eW0, const float* __restrict__ eU0,
               const float* __restrict__ eb0, const float* __restrict__ eW1,
               const float* __restrict__ eU1, const float* __restrict__ eb1,
               const float* __restrict__ dW0, const float* __restrict__ dU0,
               const float* __restrict__ db0, const float* __restrict__ dW1,
               const float* __restrict__ dU1, const float* __restrict__ db1,
               const float* __restrict__ oW,  const float* __restrict__ obv,
               float* __restrict__ out, float* __restrict__ ws)
{
    float* h0   = ws;                   // [2][32][1024]
    float* c0   = ws + 65536;           // [32][1024]
    float* h1   = ws + 98304;           // [2][32][1024]
    float* c1   = ws + 163840;          // [32][1024]
    int*   tok  = (int*)(ws + 196608);  // [32]
    float* pmax = ws + 196672;          // [500][32]
    int*   pidx = (int*)(ws + 212672);  // [500][32]

    __shared__ float red[4][64][4];
    __shared__ float hl[32][68];
    __shared__ float sval[256];
    __shared__ int   sidx[256];

    // ---- init: zero h/c, tok = BOS ----
    {
        int i = blockIdx.x * blockDim.x + threadIdx.x;
        for (; i < 196608; i += gridDim.x * blockDim.x) ws[i] = 0.0f;
        if (blockIdx.x == 0 && threadIdx.x < Bc) tok[threadIdx.x] = 1;  // BOS
    }
    gsync();

    // ---- encoder: 128 steps, layer0 then layer1 per step ----
    for (int t = 0; t < Tc; t++) {
        const int r = t & 1, w = 1 - r;
        cell_phase<Ec, 1>(eW0, eU0, eb0, nullptr, emb, src, t, nullptr,
                          h0 + r * 32768, h0 + w * 32768, c0, red);
        gsync();
        cell_phase<Hc, 0>(eW1, eU1, eb1, h0 + w * 32768, nullptr, nullptr, 0,
                          nullptr, h1 + r * 32768, h1 + w * 32768, c1, red);
        gsync();
    }

    // ---- decoder: 64 greedy steps ----
    for (int s = 0; s < Lc; s++) {
        const int r = s & 1, w = 1 - r;
        cell_phase<Ec, 2>(dW0, dU0, db0, nullptr, emb, nullptr, 0, tok,
                          h0 + r * 32768, h0 + w * 32768, c0, red);
        gsync();
        cell_phase<Hc, 0>(dW1, dU1, db1, h0 + w * 32768, nullptr, nullptr, 0,
                          nullptr, h1 + r * 32768, h1 + w * 32768, c1, red);
        gsync();
        if (blockIdx.x < 500)
            logits_phase(h1 + w * 32768, oW, obv, out, s, pmax, pidx,
                         hl, sval, sidx);
        gsync();
        if (blockIdx.x < Bc)
            argmax_phase(pmax, pidx, tok, sval, sidx);
        gsync();
    }
}

// ---------------------------------------------------------------------------
extern "C" void kernel_launch(void* const* d_in, const int* in_sizes, int n_in,
                              void* d_out, int out_size, void* d_ws, size_t ws_size,
                              hipStream_t stream)
{
    const int*   src = (const int*)d_in[0];
    const float* emb = (const float*)d_in[1];
    const float* eW0 = (const float*)d_in[2];
    const float* eU0 = (const float*)d_in[3];
    const float* eb0 = (const float*)d_in[4];
    const float* eW1 = (const float*)d_in[5];
    const float* eU1 = (const float*)d_in[6];
    const float* eb1 = (const float*)d_in[7];
    const float* dW0 = (const float*)d_in[8];
    const float* dU0 = (const float*)d_in[9];
    const float* db0 = (const float*)d_in[10];
    const float* dW1 = (const float*)d_in[11];
    const float* dU1 = (const float*)d_in[12];
    const float* db1 = (const float*)d_in[13];
    const float* oW  = (const float*)d_in[14];
    const float* obv = (const float*)d_in[15];
    float* out = (float*)d_out;
    float* ws  = (float*)d_ws;

    seq2seq_k<<<dim3(NBLK), dim3(256), 0, stream>>>(
        src, emb, eW0, eU0, eb0, eW1, eU1, eb1,
        dW0, dU0, db0, dW1, dU1, db1, oW, obv, out, ws);

    (void)in_sizes; (void)n_in; (void)out_size; (void)ws_size;
}

// Round 3
// 61768.658 us; speedup vs baseline: 1.1063x; 1.1063x over previous
//
#include <hip/hip_runtime.h>

typedef unsigned int u32;
typedef unsigned long long u64;

constexpr int Bc = 32;     // batch
constexpr int Tc = 128;    // encoder seq len
constexpr int Ec = 512;    // embed dim
constexpr int Hc = 1024;   // hidden
constexpr int Vc = 32000;  // vocab
constexpr int Lc = 64;     // max_len (decoder steps)
constexpr int NBLK = 512;  // persistent grid

__device__ __forceinline__ void ldf8(const float* p, float* x) {
    float4 a = *(const float4*)p;
    float4 b = *(const float4*)(p + 4);
    x[0] = a.x; x[1] = a.y; x[2] = a.z; x[3] = a.w;
    x[4] = b.x; x[5] = b.y; x[6] = b.z; x[7] = b.w;
}
__device__ __forceinline__ float sigm(float x) { return 1.0f / (1.0f + expf(-x)); }

// monotone map f32 -> u32 preserving order (for packed argmax keys)
__device__ __forceinline__ u32 mono(float f) {
    u32 u = __float_as_uint(f);
    return (u & 0x80000000u) ? ~u : (u | 0x80000000u);
}

// ---------------------------------------------------------------------------
// Software grid barrier, contention-free version.
//  - arrival: each block stores monotone seq into ITS OWN slot (no RMW chain)
//  - detection: block 0's 256 threads scan the 512 slots (uncached loads)
//  - wakeup: 8 replicated gate words (64B apart); <=64 pollers per line
// Monotone seqs -> no reset; graph-replay safe. Fence placement identical to
// the proven-correct round-2 barrier (release before arrive, acquire after).
// ---------------------------------------------------------------------------
__device__ __align__(64) u32 g_arrive[NBLK];
__device__ __align__(64) u32 g_gate[8 * 16];   // stride 16 u32 = 64B per gate

#define AGENT __HIP_MEMORY_SCOPE_AGENT

__device__ __forceinline__ void gsync(u32 seq) {
    const int tid = threadIdx.x;
    const int bid = blockIdx.x;
    __syncthreads();
    if (bid == 0) {
        if (tid == 0) {
            __threadfence();   // release: publish this block's writes
            __hip_atomic_store(&g_arrive[0], seq, __ATOMIC_RELAXED, AGENT);
        }
        // scan all 512 slots: thread t owns slots t and t+256
        #pragma unroll
        for (int s = tid; s < NBLK; s += 256) {
            while ((int)(__hip_atomic_load(&g_arrive[s], __ATOMIC_RELAXED,
                                           AGENT) - seq) < 0) {
                __builtin_amdgcn_s_sleep(1);
            }
        }
        __syncthreads();
        if (tid == 0) __threadfence();  // order scan -> gate; invalidate stale
        __syncthreads();
        if (tid < 8)
            __hip_atomic_store(&g_gate[tid * 16], seq, __ATOMIC_RELAXED, AGENT);
    } else {
        if (tid == 0) {
            __threadfence();   // release: publish this block's writes
            __hip_atomic_store(&g_arrive[bid], seq, __ATOMIC_RELAXED, AGENT);
            const u32* gate = &g_gate[(bid >> 6) * 16];
            while ((int)(__hip_atomic_load(gate, __ATOMIC_RELAXED,
                                           AGENT) - seq) < 0) {
                __builtin_amdgcn_s_sleep(4);
            }
            __threadfence();   // acquire: invalidate stale cached lines
        }
        __syncthreads();
    }
}

// ---------------------------------------------------------------------------
// Fused LSTM cell phase: g = x@Wih^T + h@Whh^T + b ; gates ; h_out, c.
// XMODE 0: x = fp32 buffer [B][KX]
// XMODE 1: x = emb[src[b*T + tcol]]
// XMODE 2: x = emb[decode(tok_key[b])]   (packed argmax key, agent load)
// Mapping: 512 blocks x 2 hk, 256 thr = 4 k-quarters x (32 b x 2 hk).
// ---------------------------------------------------------------------------
template<int KX, int XMODE>
__device__ __forceinline__ void cell_phase(
    const float* __restrict__ Wih, const float* __restrict__ Whh,
    const float* __restrict__ bias,
    const float* __restrict__ xbuf, const float* __restrict__ emb,
    const int* __restrict__ src, int tcol, const u64* __restrict__ tok_key,
    const float* __restrict__ h_in, float* __restrict__ h_out,
    float* __restrict__ c, float (&red)[4][64][4])
{
    const int tid = threadIdx.x;
    const int q   = tid >> 6;          // k-quarter 0..3
    const int oid = tid & 63;
    const int b   = oid & 31;
    const int hj  = oid >> 5;          // 0..1
    const int hk  = blockIdx.x * 2 + hj;

    const float* w0 = Wih + (size_t)(0 * Hc + hk) * KX;
    const float* w1 = Wih + (size_t)(1 * Hc + hk) * KX;
    const float* w2 = Wih + (size_t)(2 * Hc + hk) * KX;
    const float* w3 = Wih + (size_t)(3 * Hc + hk) * KX;
    const float* u0 = Whh + (size_t)(0 * Hc + hk) * Hc;
    const float* u1 = Whh + (size_t)(1 * Hc + hk) * Hc;
    const float* u2 = Whh + (size_t)(2 * Hc + hk) * Hc;
    const float* u3 = Whh + (size_t)(3 * Hc + hk) * Hc;

    float a0 = 0.f, a1 = 0.f, a2 = 0.f, a3 = 0.f;
    float xv[8], w[8];

    // ---- x contribution ----
    const float* xrow = nullptr;
    if constexpr (XMODE == 0) {
        xrow = xbuf + b * KX;
    } else if constexpr (XMODE == 1) {
        xrow = emb + (size_t)src[b * Tc + tcol] * Ec;
    } else {
        const u64 key = __hip_atomic_load(&tok_key[b], __ATOMIC_RELAXED, AGENT);
        const u32 idx = 0xFFFFFFFFu - (u32)(key & 0xFFFFFFFFull);
        xrow = emb + (size_t)idx * Ec;
    }
    {
        const int kq = KX / 4;
        for (int k = q * kq; k < q * kq + kq; k += 8) {
            ldf8(xrow + k, xv);
            ldf8(w0 + k, w);
            #pragma unroll
            for (int i = 0; i < 8; i++) a0 += w[i] * xv[i];
            ldf8(w1 + k, w);
            #pragma unroll
            for (int i = 0; i < 8; i++) a1 += w[i] * xv[i];
            ldf8(w2 + k, w);
            #pragma unroll
            for (int i = 0; i < 8; i++) a2 += w[i] * xv[i];
            ldf8(w3 + k, w);
            #pragma unroll
            for (int i = 0; i < 8; i++) a3 += w[i] * xv[i];
        }
    }
    // ---- h contribution ----
    {
        const float* hrow = h_in + b * Hc;
        const int kq = Hc / 4;   // 256
        for (int k = q * kq; k < q * kq + kq; k += 8) {
            ldf8(hrow + k, xv);
            ldf8(u0 + k, w);
            #pragma unroll
            for (int i = 0; i < 8; i++) a0 += w[i] * xv[i];
            ldf8(u1 + k, w);
            #pragma unroll
            for (int i = 0; i < 8; i++) a1 += w[i] * xv[i];
            ldf8(u2 + k, w);
            #pragma unroll
            for (int i = 0; i < 8; i++) a2 += w[i] * xv[i];
            ldf8(u3 + k, w);
            #pragma unroll
            for (int i = 0; i < 8; i++) a3 += w[i] * xv[i];
        }
    }

    red[q][oid][0] = a0; red[q][oid][1] = a1;
    red[q][oid][2] = a2; red[q][oid][3] = a3;
    __syncthreads();
    if (q == 0) {
        #pragma unroll
        for (int qq = 1; qq < 4; qq++) {
            a0 += red[qq][oid][0]; a1 += red[qq][oid][1];
            a2 += red[qq][oid][2]; a3 += red[qq][oid][3];
        }
        a0 += bias[0 * Hc + hk];
        a1 += bias[1 * Hc + hk];
        a2 += bias[2 * Hc + hk];
        a3 += bias[3 * Hc + hk];
        const float ig = sigm(a0), fg = sigm(a1);
        const float gv = tanhf(a2), og = sigm(a3);
        const int idx = b * Hc + hk;
        const float cn = fg * c[idx] + ig * gv;
        c[idx] = cn;
        h_out[idx] = og * tanhf(cn);
    }
}

// ---------------------------------------------------------------------------
// logits phase: logits = h1 @ out_W^T + out_b ; fp32 out; per-batch argmax
// folded in via packed-key atomicMax (first-occurrence tie rule preserved).
// Blocks 0..499 participate (500 x 64 vocab cols).
// ---------------------------------------------------------------------------
__device__ __forceinline__ void logits_phase(
    const float* __restrict__ h1, const float* __restrict__ outW,
    const float* __restrict__ outb, float* __restrict__ out, int s,
    u64* __restrict__ tok_key,
    float (&hl)[32][68], float (&sval)[256], int (&sidx)[256])
{
    const int tid = threadIdx.x;
    const int bq  = tid >> 3;        // batch row 0..31
    const int vl  = tid & 7;         // vocab lane 0..7
    const int v0  = blockIdx.x * 64;

    float acc[8];
    #pragma unroll
    for (int j = 0; j < 8; j++) acc[j] = 0.f;

    const float* wbase = outW + (size_t)(v0 + vl * 8) * Hc;

    for (int kc = 0; kc < 16; kc++) {
        #pragma unroll
        for (int i = 0; i < 2; i++) {
            const int idx4 = tid + i * 256;
            const int bb = idx4 >> 4, kq = idx4 & 15;
            *(float4*)&hl[bb][kq * 4] =
                *(const float4*)(h1 + bb * Hc + kc * 64 + kq * 4);
        }
        __syncthreads();
        #pragma unroll
        for (int i8 = 0; i8 < 8; i8++) {
            float h8[8];
            *(float4*)&h8[0] = *(const float4*)&hl[bq][i8 * 8];
            *(float4*)&h8[4] = *(const float4*)&hl[bq][i8 * 8 + 4];
            const float* wk = wbase + kc * 64 + i8 * 8;
            #pragma unroll
            for (int j = 0; j < 8; j++) {
                float w[8]; ldf8(wk + (size_t)j * Hc, w);
                float t = acc[j];
                #pragma unroll
                for (int i = 0; i < 8; i++) t += w[i] * h8[i];
                acc[j] = t;
            }
        }
        __syncthreads();
    }

    float best = -3.4e38f; int bidx = 0;
    alignas(16) float ob[8];
    #pragma unroll
    for (int j = 0; j < 8; j++) {
        const int v = v0 + vl * 8 + j;
        const float val = acc[j] + outb[v];
        ob[j] = val;
        if (val > best) { best = val; bidx = v; }   // ascending v: '>' = first occurrence
    }
    float* dst = out + (size_t)(bq * Lc + s) * Vc + v0 + vl * 8;
    *(float4*)dst       = *(const float4*)&ob[0];
    *(float4*)(dst + 4) = *(const float4*)&ob[4];

    sval[tid] = best; sidx[tid] = bidx;
    __syncthreads();
    if (vl == 0) {
        #pragma unroll
        for (int u = 1; u < 8; u++) {
            const float v2 = sval[tid + u]; const int i2 = sidx[tid + u];
            if (v2 > best || (v2 == best && i2 < bidx)) { best = v2; bidx = i2; }
        }
        // packed key: larger float wins; ties -> smaller vocab index wins
        const u64 key = ((u64)mono(best) << 32) |
                        (u64)(0xFFFFFFFFu - (u32)bidx);
        atomicMax(&tok_key[bq], key);
    }
}

// ---------------------------------------------------------------------------
// ONE persistent kernel (plain launch + contention-free grid barrier):
// init + 128 encoder steps (2 syncs each) + 64 decode steps (3 syncs each).
// 512 blocks x 256 threads = 2 blocks/CU (co-resident by __launch_bounds__).
// ---------------------------------------------------------------------------
__global__ __launch_bounds__(256, 2)
void seq2seq_k(const int* __restrict__ src, const float* __restrict__ emb,
               const float* __restrict__ eW0, const float* __restrict__ eU0,
               const float* __restrict__ eb0, const float* __restrict__ eW1,
               const float* __restrict__ eU1, const float* __restrict__ eb1,
               const float* __restrict__ dW0, const float* __restrict__ dU0,
               const float* __restrict__ db0, const float* __restrict__ dW1,
               const float* __restrict__ dU1, const float* __restrict__ db1,
               const float* __restrict__ oW,  const float* __restrict__ obv,
               float* __restrict__ out, float* __restrict__ ws)
{
    float* h0   = ws;                   // [2][32][1024]
    float* c0   = ws + 65536;           // [32][1024]
    float* h1   = ws + 98304;           // [2][32][1024]
    float* c1   = ws + 163840;          // [32][1024]
    u64*  tok_key = (u64*)(ws + 196608);  // [32] packed (mono(val), ~idx)

    __shared__ float red[4][64][4];
    __shared__ float hl[32][68];
    __shared__ float sval[256];
    __shared__ int   sidx[256];

    // seq base: stable before first barrier (no one writes gates until all
    // blocks have arrived at barrier 1, which requires this load first)
    u32 seq = __hip_atomic_load(&g_gate[0], __ATOMIC_RELAXED, AGENT);

    // ---- init: zero h/c, tok_key = BOS ----
    {
        int i = blockIdx.x * blockDim.x + threadIdx.x;
        for (; i < 196608; i += gridDim.x * blockDim.x) ws[i] = 0.0f;
        if (blockIdx.x == 0 && threadIdx.x < Bc)
            tok_key[threadIdx.x] = (u64)(0xFFFFFFFFu - 1u);  // decodes to BOS=1
    }
    gsync(++seq);

    // ---- encoder: 128 steps, layer0 then layer1 per step ----
    for (int t = 0; t < Tc; t++) {
        const int r = t & 1, w = 1 - r;
        cell_phase<Ec, 1>(eW0, eU0, eb0, nullptr, emb, src, t, nullptr,
                          h0 + r * 32768, h0 + w * 32768, c0, red);
        gsync(++seq);
        cell_phase<Hc, 0>(eW1, eU1, eb1, h0 + w * 32768, nullptr, nullptr, 0,
                          nullptr, h1 + r * 32768, h1 + w * 32768, c1, red);
        gsync(++seq);
    }

    // ---- decoder: 64 greedy steps, 3 grid syncs each ----
    for (int s = 0; s < Lc; s++) {
        const int r = s & 1, w = 1 - r;
        cell_phase<Ec, 2>(dW0, dU0, db0, nullptr, emb, nullptr, 0, tok_key,
                          h0 + r * 32768, h0 + w * 32768, c0, red);
        gsync(++seq);
        // reset tok_key strictly between last reader (cell0 above) and next
        // writer (logits below) — both separated from here by a gsync
        if (blockIdx.x == 0 && threadIdx.x < Bc) tok_key[threadIdx.x] = 0ull;
        cell_phase<Hc, 0>(dW1, dU1, db1, h0 + w * 32768, nullptr, nullptr, 0,
                          nullptr, h1 + r * 32768, h1 + w * 32768, c1, red);
        gsync(++seq);
        if (blockIdx.x < 500)
            logits_phase(h1 + w * 32768, oW, obv, out, s, tok_key,
                         hl, sval, sidx);
        gsync(++seq);
    }
}

// ---------------------------------------------------------------------------
extern "C" void kernel_launch(void* const* d_in, const int* in_sizes, int n_in,
                              void* d_out, int out_size, void* d_ws, size_t ws_size,
                              hipStream_t stream)
{
    const int*   src = (const int*)d_in[0];
    const float* emb = (const float*)d_in[1];
    const float* eW0 = (const float*)d_in[2];
    const float* eU0 = (const float*)d_in[3];
    const float* eb0 = (const float*)d_in[4];
    const float* eW1 = (const float*)d_in[5];
    const float* eU1 = (const float*)d_in[6];
    const float* eb1 = (const float*)d_in[7];
    const float* dW0 = (const float*)d_in[8];
    const float* dU0 = (const float*)d_in[9];
    const float* db0 = (const float*)d_in[10];
    const float* dW1 = (const float*)d_in[11];
    const float* dU1 = (const float*)d_in[12];
    const float* db1 = (const float*)d_in[13];
    const float* oW  = (const float*)d_in[14];
    const float* obv = (const float*)d_in[15];
    float* out = (float*)d_out;
    float* ws  = (float*)d_ws;

    seq2seq_k<<<dim3(NBLK), dim3(256), 0, stream>>>(
        src, emb, eW0, eU0, eb0, eW1, eU1, eb1,
        dW0, dU0, db0, dW1, dU1, db1, oW, obv, out, ws);

    (void)in_sizes; (void)n_in; (void)out_size; (void)ws_size;
}